// Round 1
// baseline (983.891 us; speedup 1.0000x reference)
//
#include <hip/hip_runtime.h>

typedef __bf16 bf16_t;
typedef bf16_t bf16x8 __attribute__((ext_vector_type(8)));
typedef float f32x4 __attribute__((ext_vector_type(4)));
typedef unsigned short u16x8 __attribute__((ext_vector_type(8)));

#define MFMA16(a, b, c) __builtin_amdgcn_mfma_f32_16x16x32_bf16((a), (b), (c), 0, 0, 0)

__device__ __forceinline__ unsigned short f2bf(float f) {
    unsigned int u = __float_as_uint(f);
    u += 0x7fff + ((u >> 16) & 1);   // RNE; inputs are finite
    return (unsigned short)(u >> 16);
}
__device__ __forceinline__ float bf2f(unsigned short s) {
    return __uint_as_float(((unsigned int)s) << 16);
}

// ---------------------------------------------------------------- cast f32->bf16
__global__ __launch_bounds__(256) void cast_f32_bf16(const float* __restrict__ src,
                                                     unsigned short* __restrict__ dst, int n) {
    int i = (blockIdx.x * 256 + threadIdx.x) * 4;
    if (i + 3 < n) {
        float4 f = *reinterpret_cast<const float4*>(src + i);
        union { unsigned short u[4]; uint2 v; } o;
        o.u[0] = f2bf(f.x); o.u[1] = f2bf(f.y); o.u[2] = f2bf(f.z); o.u[3] = f2bf(f.w);
        *reinterpret_cast<uint2*>(dst + i) = o.v;
    }
}

// ---------------------------------------------------------------- GEMM: C = A @ W^T
// A [M,K] bf16 row-major, W [N,K] bf16 row-major (einsum 'bsd,ed->bse' => x @ W^T).
// 128x128 tile, BK=32, 4 waves (2x2), 16x16x32 bf16 MFMA. z selects (W,O) for fused QKV.
template <bool OUTF32>
__global__ __launch_bounds__(256) void gemm_bt(const unsigned short* __restrict__ A,
                                               const unsigned short* __restrict__ W0,
                                               const unsigned short* __restrict__ W1,
                                               const unsigned short* __restrict__ W2,
                                               void* O0, void* O1, void* O2,
                                               int M, int N, int K) {
    const unsigned short* W = W0; void* O = O0;
    if (blockIdx.z == 1) { W = W1; O = O1; }
    else if (blockIdx.z == 2) { W = W2; O = O2; }

    __shared__ unsigned short As[128][40];   // +8 pad: 80B row stride -> worst 2-way (free)
    __shared__ unsigned short Ws[128][40];

    int t = threadIdx.x;
    int lane = t & 63, wave = t >> 6;
    int li = lane & 15, lg = lane >> 4;
    int wm = wave >> 1, wn = wave & 1;
    int m0 = blockIdx.y * 128, n0 = blockIdx.x * 128;

    int srow = t >> 1;            // 0..127
    int scol = (t & 1) << 4;      // 0 | 16
    const unsigned short* Aload = A + (size_t)(m0 + srow) * K + scol;
    const unsigned short* Wload = W + (size_t)(n0 + srow) * K + scol;

    f32x4 acc[4][4];
#pragma unroll
    for (int i = 0; i < 4; i++)
#pragma unroll
        for (int j = 0; j < 4; j++) acc[i][j] = (f32x4){0.f, 0.f, 0.f, 0.f};

    for (int kt = 0; kt < K; kt += 32) {
        bf16x8 a0 = *reinterpret_cast<const bf16x8*>(Aload + kt);
        bf16x8 a1 = *reinterpret_cast<const bf16x8*>(Aload + kt + 8);
        bf16x8 w0 = *reinterpret_cast<const bf16x8*>(Wload + kt);
        bf16x8 w1 = *reinterpret_cast<const bf16x8*>(Wload + kt + 8);
        __syncthreads();
        *reinterpret_cast<bf16x8*>(&As[srow][scol])     = a0;
        *reinterpret_cast<bf16x8*>(&As[srow][scol + 8]) = a1;
        *reinterpret_cast<bf16x8*>(&Ws[srow][scol])     = w0;
        *reinterpret_cast<bf16x8*>(&Ws[srow][scol + 8]) = w1;
        __syncthreads();
        bf16x8 af[4], wf[4];
#pragma unroll
        for (int ms = 0; ms < 4; ms++)
            af[ms] = *reinterpret_cast<const bf16x8*>(&As[wm * 64 + ms * 16 + li][lg * 8]);
#pragma unroll
        for (int ns = 0; ns < 4; ns++)
            wf[ns] = *reinterpret_cast<const bf16x8*>(&Ws[wn * 64 + ns * 16 + li][lg * 8]);
#pragma unroll
        for (int ms = 0; ms < 4; ms++)
#pragma unroll
            for (int ns = 0; ns < 4; ns++)
                acc[ms][ns] = MFMA16(af[ms], wf[ns], acc[ms][ns]);
    }

#pragma unroll
    for (int ms = 0; ms < 4; ms++)
#pragma unroll
        for (int ns = 0; ns < 4; ns++) {
            int col = n0 + wn * 64 + ns * 16 + li;
#pragma unroll
            for (int r = 0; r < 4; r++) {
                int row = m0 + wm * 64 + ms * 16 + lg * 4 + r;   // C: col=lane&15, row=(lane>>4)*4+r
                if (OUTF32) ((float*)O)[(size_t)row * N + col] = acc[ms][ns][r];
                else ((unsigned short*)O)[(size_t)row * N + col] = f2bf(acc[ms][ns][r]);
            }
        }
}

// ---------------------------------------------------------------- RoPE + relayout
// qraw/kraw [B*S, D] bf16 -> qb/kb [B,H,S,64] bf16; q additionally scaled by 1/8.
__global__ __launch_bounds__(256) void rope_kernel(const unsigned short* __restrict__ qraw,
                                                   const unsigned short* __restrict__ kraw,
                                                   const float* __restrict__ cosT,
                                                   const float* __restrict__ sinT,
                                                   unsigned short* __restrict__ qb,
                                                   unsigned short* __restrict__ kb) {
    int tid = blockIdx.x * 256 + threadIdx.x;          // 2 * 2^21 threads
    int tsel = tid >> 21;
    int r = tid & ((1 << 21) - 1);
    int t = r & 31;
    int h = (r >> 5) & 15;
    int s = (r >> 9) & 2047;
    int b = r >> 20;
    const unsigned short* src = tsel ? kraw : qraw;
    unsigned short* dst = tsel ? kb : qb;
    float scale = tsel ? 1.0f : 0.125f;                // fold 1/sqrt(64) into q

    size_t sidx = (size_t)(b * 2048 + s) * 1024 + h * 64 + 2 * t;
    unsigned int v = *reinterpret_cast<const unsigned int*>(src + sidx);
    float t0 = bf2f((unsigned short)(v & 0xffff));
    float t1 = bf2f((unsigned short)(v >> 16));
    float c = cosT[s * 32 + t], sn = sinT[s * 32 + t];
    float o0 = (t0 * c - t1 * sn) * scale;
    float o1 = (t0 * sn + t1 * c) * scale;
    unsigned int ov = (unsigned int)f2bf(o0) | ((unsigned int)f2bf(o1) << 16);
    size_t didx = ((size_t)(b * 16 + h) * 2048 + s) * 64 + 2 * t;
    *reinterpret_cast<unsigned int*>(dst + didx) = ov;
}

// ---------------------------------------------------------------- V transpose
// vraw [B*S, D] bf16 -> vtb [B,H,64,S] bf16 (so PV B-fragments are contiguous along j)
__global__ __launch_bounds__(256) void transpose_v(const unsigned short* __restrict__ vraw,
                                                   unsigned short* __restrict__ vtb) {
    int bh = blockIdx.y, b = bh >> 4, h = bh & 15;
    int s0 = blockIdx.x * 64;
    __shared__ unsigned short vt[64][72];
    int t = threadIdx.x;
    int sr = t >> 2, c4 = (t & 3) * 16;
    const unsigned short* src = vraw + (size_t)(b * 2048 + s0 + sr) * 1024 + h * 64 + c4;
    *reinterpret_cast<u16x8*>(&vt[sr][c4])     = *reinterpret_cast<const u16x8*>(src);
    *reinterpret_cast<u16x8*>(&vt[sr][c4 + 8]) = *reinterpret_cast<const u16x8*>(src + 8);
    __syncthreads();
    int d = t >> 2, sc = (t & 3) * 16;
    u16x8 o0, o1;
#pragma unroll
    for (int i = 0; i < 8; i++) { o0[i] = vt[sc + i][d]; o1[i] = vt[sc + 8 + i][d]; }
    unsigned short* dst = vtb + ((size_t)bh * 64 + d) * 2048 + s0 + sc;
    *reinterpret_cast<u16x8*>(dst)     = o0;
    *reinterpret_cast<u16x8*>(dst + 8) = o1;
}

// ---------------------------------------------------------------- fused attention
// grid (S/64, B*H), 4 independent waves x 16 query rows. Pass1: online (m,l) per lane,
// merged across the 16-lane column group. Pass2: recompute scores, write normalized
// weights (fp32), entropy, and PV via LDS-transposed P fragments.
__global__ __launch_bounds__(256) void attn_kernel(const unsigned short* __restrict__ qb,
                                                   const unsigned short* __restrict__ kb,
                                                   const unsigned short* __restrict__ vtb,
                                                   float* __restrict__ attn_out,
                                                   float* __restrict__ ent_out,
                                                   unsigned short* __restrict__ ctx) {
    const int S = 2048, H = 16, HD = 64;
    int bh = blockIdx.y;
    int b = bh >> 4, h = bh & 15;
    int w = threadIdx.x >> 6;
    int lane = threadIdx.x & 63;
    int li = lane & 15, lg = lane >> 4;
    int i0 = blockIdx.x * 64 + w * 16;

    __shared__ unsigned short plds[4][16][40];   // per-wave P tile, 80B row stride

    const unsigned short* qrow = qb + ((size_t)bh * S + i0) * HD;
    bf16x8 qf0 = *reinterpret_cast<const bf16x8*>(qrow + li * HD + lg * 8);        // k 0..31
    bf16x8 qf1 = *reinterpret_cast<const bf16x8*>(qrow + li * HD + 32 + lg * 8);   // k 32..63

    const unsigned short* kbase = kb + (size_t)bh * S * HD;
    const unsigned short* vbase = vtb + (size_t)bh * HD * S;

    float m[4], lsum[4];
#pragma unroll
    for (int r = 0; r < 4; r++) { m[r] = -1e30f; lsum[r] = 0.f; }

    // ---- pass 1: online max/sumexp (per-lane over its 128 columns)
    for (int j0 = 0; j0 < S; j0 += 16) {
        const unsigned short* kt = kbase + (size_t)(j0 + li) * HD + lg * 8;
        bf16x8 kf0 = *reinterpret_cast<const bf16x8*>(kt);
        bf16x8 kf1 = *reinterpret_cast<const bf16x8*>(kt + 32);
        f32x4 sacc = (f32x4){0.f, 0.f, 0.f, 0.f};
        sacc = MFMA16(qf0, kf0, sacc);
        sacc = MFMA16(qf1, kf1, sacc);
#pragma unroll
        for (int r = 0; r < 4; r++) {
            float sc = sacc[r];
            float mn = fmaxf(m[r], sc);
            lsum[r] = lsum[r] * __expf(m[r] - mn) + __expf(sc - mn);
            m[r] = mn;
        }
    }
    // merge (m,l) across the 16 column lanes
#pragma unroll
    for (int mask = 1; mask < 16; mask <<= 1) {
#pragma unroll
        for (int r = 0; r < 4; r++) {
            float om = __shfl_xor(m[r], mask, 64);
            float ol = __shfl_xor(lsum[r], mask, 64);
            float mn = fmaxf(m[r], om);
            lsum[r] = lsum[r] * __expf(m[r] - mn) + ol * __expf(om - mn);
            m[r] = mn;
        }
    }
    float invl[4];
#pragma unroll
    for (int r = 0; r < 4; r++) invl[r] = 1.0f / lsum[r];

    // ---- pass 2: recompute scores, write weights + entropy, accumulate PV
    f32x4 pv[4];
#pragma unroll
    for (int d4 = 0; d4 < 4; d4++) pv[d4] = (f32x4){0.f, 0.f, 0.f, 0.f};
    float ent[4] = {0.f, 0.f, 0.f, 0.f};
    size_t abase = (((size_t)b * S + i0) * H + h) * S;

    for (int jc = 0; jc < S; jc += 32) {
#pragma unroll
        for (int js = 0; js < 2; js++) {
            int j0 = jc + js * 16;
            const unsigned short* kt = kbase + (size_t)(j0 + li) * HD + lg * 8;
            bf16x8 kf0 = *reinterpret_cast<const bf16x8*>(kt);
            bf16x8 kf1 = *reinterpret_cast<const bf16x8*>(kt + 32);
            f32x4 sacc = (f32x4){0.f, 0.f, 0.f, 0.f};
            sacc = MFMA16(qf0, kf0, sacc);
            sacc = MFMA16(qf1, kf1, sacc);
#pragma unroll
            for (int r = 0; r < 4; r++) {
                float p = __expf(sacc[r] - m[r]) * invl[r];
                attn_out[abase + (size_t)(lg * 4 + r) * (H * S) + j0 + li] = p;
                ent[r] = fmaf(p, __log2f(p + 1e-9f), ent[r]);
                plds[w][lg * 4 + r][js * 16 + li] = f2bf(p);
            }
        }
        // PV: A = P from LDS (row=li, k=lg*8..+8), B = V^T contiguous along j
        bf16x8 pf = *reinterpret_cast<const bf16x8*>(&plds[w][li][lg * 8]);
#pragma unroll
        for (int d4 = 0; d4 < 4; d4++) {
            bf16x8 vf = *reinterpret_cast<const bf16x8*>(vbase + (size_t)(d4 * 16 + li) * S + jc + lg * 8);
            pv[d4] = MFMA16(pf, vf, pv[d4]);
        }
    }

    // entropy: reduce across the 16 column lanes, write per row
#pragma unroll
    for (int mask = 1; mask < 16; mask <<= 1)
#pragma unroll
        for (int r = 0; r < 4; r++) ent[r] += __shfl_xor(ent[r], mask, 64);
    if (li == 0) {
#pragma unroll
        for (int r = 0; r < 4; r++)
            ent_out[((size_t)b * S + i0 + lg * 4 + r) * H + h] = -ent[r];
    }
    // context (pre-output-projection), bf16 [B*S, D]
#pragma unroll
    for (int d4 = 0; d4 < 4; d4++)
#pragma unroll
        for (int r = 0; r < 4; r++)
            ctx[((size_t)b * S + i0 + lg * 4 + r) * 1024 + h * 64 + d4 * 16 + li] = f2bf(pv[d4][r]);
}

// ----------------------------------------------------------------
extern "C" void kernel_launch(void* const* d_in, const int* in_sizes, int n_in,
                              void* d_out, int out_size, void* d_ws, size_t ws_size,
                              hipStream_t stream) {
    const float* x    = (const float*)d_in[0];
    const float* cosT = (const float*)d_in[1];
    const float* sinT = (const float*)d_in[2];
    const float* wq   = (const float*)d_in[3];
    const float* wk   = (const float*)d_in[4];
    const float* wv   = (const float*)d_in[5];
    const float* wo   = (const float*)d_in[6];

    const int B = 2, S = 2048, D = 1024, H = 16;
    const int M = B * S;   // 4096

    float* out_final = (float*)d_out;
    float* attn_out  = out_final + (size_t)M * D;                  // 4,194,304
    float* ent_out   = attn_out + (size_t)B * S * H * S;           // +134,217,728

    char* ws = (char*)d_ws;
    const size_t MB = 1u << 20;
    unsigned short* xb   = (unsigned short*)(ws + 0 * MB);    // 8 MB
    unsigned short* wqb  = (unsigned short*)(ws + 8 * MB);    // 2 MB
    unsigned short* wkb  = (unsigned short*)(ws + 10 * MB);
    unsigned short* wvb  = (unsigned short*)(ws + 12 * MB);
    unsigned short* wob  = (unsigned short*)(ws + 14 * MB);
    unsigned short* qraw = (unsigned short*)(ws + 16 * MB);   // 8 MB each
    unsigned short* kraw = (unsigned short*)(ws + 24 * MB);
    unsigned short* vraw = (unsigned short*)(ws + 32 * MB);
    unsigned short* qbb  = (unsigned short*)(ws + 40 * MB);
    unsigned short* kbb  = (unsigned short*)(ws + 48 * MB);
    unsigned short* vtb  = (unsigned short*)(ws + 56 * MB);
    unsigned short* ctx  = (unsigned short*)(ws + 64 * MB);   // ends at 72 MB

    cast_f32_bf16<<<4096, 256, 0, stream>>>(x, xb, M * D);
    cast_f32_bf16<<<1024, 256, 0, stream>>>(wq, wqb, D * D);
    cast_f32_bf16<<<1024, 256, 0, stream>>>(wk, wkb, D * D);
    cast_f32_bf16<<<1024, 256, 0, stream>>>(wv, wvb, D * D);
    cast_f32_bf16<<<1024, 256, 0, stream>>>(wo, wob, D * D);

    // fused QKV projection (z selects weight/output)
    gemm_bt<false><<<dim3(D / 128, M / 128, 3), 256, 0, stream>>>(
        xb, wqb, wkb, wvb, qraw, kraw, vraw, M, D, D);

    rope_kernel<<<16384, 256, 0, stream>>>(qraw, kraw, cosT, sinT, qbb, kbb);
    transpose_v<<<dim3(S / 64, B * H), 256, 0, stream>>>(vraw, vtb);

    attn_kernel<<<dim3(S / 64, B * H), 256, 0, stream>>>(qbb, kbb, vtb, attn_out, ent_out, ctx);

    // output projection -> fp32 d_out
    gemm_bt<true><<<dim3(D / 128, M / 128, 1), 256, 0, stream>>>(
        ctx, wob, wob, wob, d_out, d_out, d_out, M, D, D);
}